// Round 1
// baseline (162.526 us; speedup 1.0000x reference)
//
#include <hip/hip_runtime.h>

// Problem constants (from reference):
//   B=4, S=2048, D=1024, N=65536, K=16  -> T = B*S = 8192 tokens
#define TOKENS 8192
#define DIM    1024
#define TOPK   16
#define NTHREADS 256   // 256 threads * float4 = 1024 floats = one full row pass

__global__ __launch_bounds__(NTHREADS) void kc_kernel(
    const float* __restrict__ x,      // [T, D]
    const float* __restrict__ emb,    // [N, D]
    const float* __restrict__ w,      // [N, D]
    const float* __restrict__ gate,   // [T, K]
    const int*   __restrict__ idx,    // [T, K]
    float*       __restrict__ out)    // [T, D]
{
    const int t    = blockIdx.x;
    const int tid  = threadIdx.x;
    const int lane = tid & 63;
    const int wave = tid >> 6;

    __shared__ int   sidx[TOPK];
    __shared__ float sgated[TOPK];
    __shared__ float swpart[4][TOPK];

    if (tid < TOPK) sidx[tid] = idx[(size_t)t * TOPK + tid];
    __syncthreads();

    // This thread's float4 slice of x[t,:]
    const float4 xv = *reinterpret_cast<const float4*>(x + (size_t)t * DIM + tid * 4);

    // ---- Phase 1: activations  act[k] = dot(x, emb[idx[k]]) ----
    float part[TOPK];
    #pragma unroll
    for (int k = 0; k < TOPK; ++k) {
        const float4 ev = *reinterpret_cast<const float4*>(
            emb + (size_t)sidx[k] * DIM + tid * 4);
        part[k] = xv.x * ev.x + xv.y * ev.y + xv.z * ev.z + xv.w * ev.w;
    }

    // 64-lane wave reduction for each of the 16 partials
    #pragma unroll
    for (int k = 0; k < TOPK; ++k) {
        float v = part[k];
        #pragma unroll
        for (int off = 32; off >= 1; off >>= 1)
            v += __shfl_xor(v, off, 64);
        part[k] = v;
    }
    if (lane == 0) {
        #pragma unroll
        for (int k = 0; k < TOPK; ++k) swpart[wave][k] = part[k];
    }
    __syncthreads();

    if (tid < TOPK) {
        const float a = swpart[0][tid] + swpart[1][tid] +
                        swpart[2][tid] + swpart[3][tid];
        sgated[tid] = a * gate[(size_t)t * TOPK + tid];
    }
    __syncthreads();

    // ---- Phase 2: emit  out = sum_k gated[k] * w[idx[k]] ----
    float ax = 0.f, ay = 0.f, az = 0.f, aw = 0.f;
    #pragma unroll
    for (int k = 0; k < TOPK; ++k) {
        const float g = sgated[k];
        const float4 wv = *reinterpret_cast<const float4*>(
            w + (size_t)sidx[k] * DIM + tid * 4);
        ax += g * wv.x; ay += g * wv.y; az += g * wv.z; aw += g * wv.w;
    }
    float4 acc = make_float4(ax, ay, az, aw);
    *reinterpret_cast<float4*>(out + (size_t)t * DIM + tid * 4) = acc;
}

extern "C" void kernel_launch(void* const* d_in, const int* in_sizes, int n_in,
                              void* d_out, int out_size, void* d_ws, size_t ws_size,
                              hipStream_t stream) {
    const float* x    = (const float*)d_in[0];  // [B,S,D]
    const float* emb  = (const float*)d_in[1];  // [N,D]
    const float* w    = (const float*)d_in[2];  // [N,D]
    const float* gate = (const float*)d_in[3];  // [B,S,K]
    const int*   idx  = (const int*)d_in[4];    // [B,S,K]
    float*       out  = (float*)d_out;          // [B,S,D]

    kc_kernel<<<TOKENS, NTHREADS, 0, stream>>>(x, emb, w, gate, idx, out);
}